// Round 7
// baseline (791.179 us; speedup 1.0000x reference)
//
#include <hip/hip_runtime.h>
#include <hip/hip_bf16.h>

#define N_NODES 100000
#define N_EDGES 1600000
#define DIM 128

#define NB    782      // buckets = ceil(100000/128)
#define NPB   128      // nodes per bucket
#define BSTR  2944     // bucket array stride
#define CHUNK 4096     // edges per passA block

typedef __attribute__((ext_vector_type(8))) short bf16x8;
typedef __attribute__((ext_vector_type(4))) float f32x4;

__device__ __forceinline__ short f2bf(float f) {
    union { float f; unsigned u; } v; v.f = f;
    unsigned r = (v.u + 0x7fff + ((v.u >> 16) & 1)) >> 16;
    return (short)r;
}
__device__ __forceinline__ unsigned pk(float lo, float hi) {
    return (unsigned)(unsigned short)f2bf(lo) | ((unsigned)(unsigned short)f2bf(hi) << 16);
}
__device__ __forceinline__ float bl(unsigned p) {
    union { unsigned u; float f; } v; v.u = p << 16; return v.f;
}
__device__ __forceinline__ float bh(unsigned p) {
    union { unsigned u; float f; } v; v.u = p & 0xffff0000u; return v.f;
}
__device__ __forceinline__ float bfs(short s) {
    union { unsigned u; float f; } v; v.u = ((unsigned)(unsigned short)s) << 16; return v.f;
}

// ---------------------------------------------------------------------------
// prep: fused f32->bf16 convert of x + weight transpose [k][n]->[n][k] bf16
// ---------------------------------------------------------------------------
__global__ __launch_bounds__(256) void prep_kernel(
    const float* __restrict__ x, unsigned short* __restrict__ xb,
    const float* __restrict__ W0, const float* __restrict__ W1,
    const float* __restrict__ W2, const float* __restrict__ W3,
    const float* __restrict__ W4, const float* __restrict__ W5,
    unsigned short* __restrict__ T)
{
    int b = blockIdx.x, t = threadIdx.x;
    if (b < 6250) {
        long long i = (long long)b * 256 + t;
        const float4* p = (const float4*)(x + i * 8);
        float4 a = p[0], c = p[1];
        uint4 o;
        o.x = pk(a.x, a.y); o.y = pk(a.z, a.w);
        o.z = pk(c.x, c.y); o.w = pk(c.z, c.w);
        *(uint4*)(xb + i * 8) = o;
    } else {
        int idx = (b - 6250) * 256 + t;
        int m = idx >> 14, rem = idx & 16383;
        int n = rem >> 7, k = rem & 127;
        const float* W = (m == 0) ? W0 : (m == 1) ? W1 : (m == 2) ? W2
                       : (m == 3) ? W3 : (m == 4) ? W4 : W5;
        T[(size_t)m * DIM * DIM + n * DIM + k] = (unsigned short)f2bf(W[k * DIM + n]);
    }
}

// ---------------------------------------------------------------------------
// CSR pass A: bucket edges by dst>>7 (packed 4B recs)
// ---------------------------------------------------------------------------
__global__ __launch_bounds__(256) void bucketA_kernel(
    const int* __restrict__ src, const int* __restrict__ dst,
    int* __restrict__ gcur, unsigned* __restrict__ barr)
{
    __shared__ int cnt[NB];
    __shared__ int base[NB];
    const int t = threadIdx.x;
    const long long e0 = (long long)blockIdx.x * CHUNK;
    const int ecnt = (int)((e0 + CHUNK <= N_EDGES) ? CHUNK : (N_EDGES - e0));

    for (int i = t; i < NB; i += 256) cnt[i] = 0;
    __syncthreads();
    for (int i = t; i < ecnt; i += 256)
        atomicAdd(&cnt[dst[e0 + i] >> 7], 1);
    __syncthreads();
    for (int i = t; i < NB; i += 256) {
        int c = cnt[i];
        base[i] = c ? atomicAdd(&gcur[i], c) : 0;
        cnt[i] = 0;
    }
    __syncthreads();
    for (int i = t; i < ecnt; i += 256) {
        int d = dst[e0 + i], s = src[e0 + i];
        int bk = d >> 7;
        int r = atomicAdd(&cnt[bk], 1);
        barr[(long long)bk * BSTR + base[bk] + r] =
            (unsigned)s | ((unsigned)(d & 127) << 20);
    }
}

// ---------------------------------------------------------------------------
// CSR: exclusive scan of bucket totals (1 wave)
// ---------------------------------------------------------------------------
__global__ __launch_bounds__(64) void scanb_kernel(
    const int* __restrict__ gcur, int* __restrict__ cbase)
{
    int lane = threadIdx.x;
    int carry = 0;
    for (int b0 = 0; b0 < NB; b0 += 64) {
        int v = (b0 + lane < NB) ? gcur[b0 + lane] : 0;
        int s = v;
#pragma unroll
        for (int ofs = 1; ofs < 64; ofs <<= 1) {
            int u = __shfl_up(s, ofs);
            if (lane >= ofs) s += u;
        }
        if (b0 + lane < NB) cbase[b0 + lane] = carry + s - v;
        carry += __shfl(s, 63);
    }
    if (lane == 0) cbase[NB] = carry;
}

// ---------------------------------------------------------------------------
// CSR pass B: per-bucket node counts + scan -> off[], compact csr[]
// ---------------------------------------------------------------------------
__global__ __launch_bounds__(256) void bucketB_kernel(
    const unsigned* __restrict__ barr, const int* __restrict__ gcur,
    const int* __restrict__ cbase, int* __restrict__ off, int* __restrict__ csr)
{
    __shared__ int cnt[NPB];
    __shared__ int cur[NPB];
    __shared__ int sbase, sn;
    const int b = blockIdx.x, t = threadIdx.x;
    if (t < NPB) cnt[t] = 0;
    if (t == 0) { sbase = cbase[b]; sn = gcur[b]; }
    __syncthreads();
    const int n = sn;
    const unsigned* be = barr + (long long)b * BSTR;
    for (int i = t; i < n; i += 256)
        atomicAdd(&cnt[(be[i] >> 20) & 127], 1);
    __syncthreads();
    if (t < 64) {
        int carry = 0;
#pragma unroll
        for (int k = 0; k < 2; ++k) {
            int idx = k * 64 + t;
            int v = cnt[idx], s = v;
#pragma unroll
            for (int ofs = 1; ofs < 64; ofs <<= 1) {
                int u = __shfl_up(s, ofs);
                if (t >= ofs) s += u;
            }
            cur[idx] = carry + s - v;
            carry += __shfl(s, 63);
        }
    }
    __syncthreads();
    if (t < NPB) {
        int node = b * NPB + t;
        if (node < N_NODES) off[node] = sbase + cur[t];
    }
    if (b == NB - 1 && t == 0) off[N_NODES] = cbase[NB];
    __syncthreads();
    for (int i = t; i < n; i += 256) {
        unsigned r = be[i];
        int j = (r >> 20) & 127;
        int p = atomicAdd(&cur[j], 1);
        csr[sbase + p] = (int)(r & 0xFFFFF);
    }
}

// ---------------------------------------------------------------------------
// Fused GIN layer: gather (phase 0) + MLP (2 MFMA GEMMs) in one kernel.
// Block = 128 rows, 4 waves. Phase 0: wave w gathers rows w*32..w*32+31
// (A = x_self + sum_neighbors) in bf16 straight into the LDS A-tile.
// Co-resident blocks overlap gather (memory) with GEMM (MFMA).
// mode 1: store bf16 relu(C) to outb. mode 2: fused concat-readout.
// ---------------------------------------------------------------------------
__global__ __launch_bounds__(256, 3) void gin_fused_kernel(
    const unsigned short* __restrict__ xb,   // gather input [N][128] bf16
    const int* __restrict__ off, const int* __restrict__ csr,
    const unsigned short* __restrict__ Wt1, const float* __restrict__ b1,
    const unsigned short* __restrict__ Wt2, const float* __restrict__ b2,
    unsigned short* __restrict__ outb,
    const unsigned short* __restrict__ hb0, const unsigned short* __restrict__ hb1,
    const float* __restrict__ Wm, const float* __restrict__ bm,
    float* __restrict__ out, int mode, int N)
{
    __shared__ short S[128][136];   // 34.8 KB; A -> H -> C in turn

    const int t = threadIdx.x;
    const int w = t >> 6, lane = t & 63;
    const long long row0 = (long long)blockIdx.x * 128;

    // ---- phase 0: gather. 4 edge-groups x 16 lanes x 16B, 4-deep unroll ----
    {
        const int g = lane >> 4, l4 = lane & 15;
        for (int i = 0; i < 32; ++i) {
            const int r = w * 32 + i;
            const long long node = row0 + r;
            float acc[8] = {0.f, 0.f, 0.f, 0.f, 0.f, 0.f, 0.f, 0.f};
            if (node < N) {
                const int beg = off[node], end = off[node + 1];
                int j = beg + g;
                for (; j + 12 < end; j += 16) {
                    int s0 = csr[j], s1 = csr[j + 4], s2 = csr[j + 8], s3 = csr[j + 12];
                    uint4 v0 = *(const uint4*)(xb + (long long)s0 * DIM + l4 * 8);
                    uint4 v1 = *(const uint4*)(xb + (long long)s1 * DIM + l4 * 8);
                    uint4 v2 = *(const uint4*)(xb + (long long)s2 * DIM + l4 * 8);
                    uint4 v3 = *(const uint4*)(xb + (long long)s3 * DIM + l4 * 8);
                    acc[0] += (bl(v0.x) + bl(v1.x)) + (bl(v2.x) + bl(v3.x));
                    acc[1] += (bh(v0.x) + bh(v1.x)) + (bh(v2.x) + bh(v3.x));
                    acc[2] += (bl(v0.y) + bl(v1.y)) + (bl(v2.y) + bl(v3.y));
                    acc[3] += (bh(v0.y) + bh(v1.y)) + (bh(v2.y) + bh(v3.y));
                    acc[4] += (bl(v0.z) + bl(v1.z)) + (bl(v2.z) + bl(v3.z));
                    acc[5] += (bh(v0.z) + bh(v1.z)) + (bh(v2.z) + bh(v3.z));
                    acc[6] += (bl(v0.w) + bl(v1.w)) + (bl(v2.w) + bl(v3.w));
                    acc[7] += (bh(v0.w) + bh(v1.w)) + (bh(v2.w) + bh(v3.w));
                }
                for (; j < end; j += 4) {
                    int s = csr[j];
                    uint4 v = *(const uint4*)(xb + (long long)s * DIM + l4 * 8);
                    acc[0] += bl(v.x); acc[1] += bh(v.x);
                    acc[2] += bl(v.y); acc[3] += bh(v.y);
                    acc[4] += bl(v.z); acc[5] += bh(v.z);
                    acc[6] += bl(v.w); acc[7] += bh(v.w);
                }
            }
#pragma unroll
            for (int k = 0; k < 8; ++k) {
                acc[k] += __shfl_xor(acc[k], 16);
                acc[k] += __shfl_xor(acc[k], 32);
            }
            if (g == 0) {
                if (node < N) {
                    uint4 sv = *(const uint4*)(xb + node * DIM + l4 * 8);
                    acc[0] += bl(sv.x); acc[1] += bh(sv.x);
                    acc[2] += bl(sv.y); acc[3] += bh(sv.y);
                    acc[4] += bl(sv.z); acc[5] += bh(sv.z);
                    acc[6] += bl(sv.w); acc[7] += bh(sv.w);
                }
                uint4 o;
                o.x = pk(acc[0], acc[1]); o.y = pk(acc[2], acc[3]);
                o.z = pk(acc[4], acc[5]); o.w = pk(acc[6], acc[7]);
                *(uint4*)&S[r][l4 * 8] = o;
            }
        }
    }
    __syncthreads();

    const int wr = (w >> 1) * 64, wc = (w & 1) * 64;
    const int fr = lane & 15, kg = lane >> 4;

    // ---- GEMM1: H = relu(A @ W1 + b1) ----
    f32x4 acc[4][4] = {};
#pragma unroll
    for (int k0 = 0; k0 < 128; k0 += 32) {
        bf16x8 a[4], b[4];
#pragma unroll
        for (int mi = 0; mi < 4; ++mi)
            a[mi] = *(const bf16x8*)&S[wr + mi * 16 + fr][k0 + kg * 8];
#pragma unroll
        for (int ni = 0; ni < 4; ++ni)
            b[ni] = *(const bf16x8*)(Wt1 + (long long)(wc + ni * 16 + fr) * DIM + k0 + kg * 8);
#pragma unroll
        for (int mi = 0; mi < 4; ++mi)
#pragma unroll
            for (int ni = 0; ni < 4; ++ni)
                acc[mi][ni] = __builtin_amdgcn_mfma_f32_16x16x32_bf16(
                    a[mi], b[ni], acc[mi][ni], 0, 0, 0);
    }
    __syncthreads();   // all waves done reading A

    {
        float bia[4];
#pragma unroll
        for (int ni = 0; ni < 4; ++ni) bia[ni] = b1[wc + ni * 16 + fr];
#pragma unroll
        for (int mi = 0; mi < 4; ++mi)
#pragma unroll
            for (int ni = 0; ni < 4; ++ni)
#pragma unroll
                for (int j = 0; j < 4; ++j) {
                    int rr = wr + mi * 16 + kg * 4 + j;
                    int cc = wc + ni * 16 + fr;
                    float hv = acc[mi][ni][j] + bia[ni];
                    S[rr][cc] = f2bf(hv > 0.f ? hv : 0.f);
                }
    }
    __syncthreads();

    // ---- GEMM2: C = H @ W2 + b2 ----
    f32x4 acc2[4][4] = {};
#pragma unroll
    for (int k0 = 0; k0 < 128; k0 += 32) {
        bf16x8 a[4], b[4];
#pragma unroll
        for (int mi = 0; mi < 4; ++mi)
            a[mi] = *(const bf16x8*)&S[wr + mi * 16 + fr][k0 + kg * 8];
#pragma unroll
        for (int ni = 0; ni < 4; ++ni)
            b[ni] = *(const bf16x8*)(Wt2 + (long long)(wc + ni * 16 + fr) * DIM + k0 + kg * 8);
#pragma unroll
        for (int mi = 0; mi < 4; ++mi)
#pragma unroll
            for (int ni = 0; ni < 4; ++ni)
                acc2[mi][ni] = __builtin_amdgcn_mfma_f32_16x16x32_bf16(
                    a[mi], b[ni], acc2[mi][ni], 0, 0, 0);
    }
    __syncthreads();   // all waves done reading H

    {
        float bia[4];
#pragma unroll
        for (int ni = 0; ni < 4; ++ni) bia[ni] = b2[wc + ni * 16 + fr];
#pragma unroll
        for (int mi = 0; mi < 4; ++mi)
#pragma unroll
            for (int ni = 0; ni < 4; ++ni)
#pragma unroll
                for (int j = 0; j < 4; ++j) {
                    int rr = wr + mi * 16 + kg * 4 + j;
                    int cc = wc + ni * 16 + fr;
                    float v2 = acc2[mi][ni][j] + bia[ni];
                    if (mode == 1 && v2 < 0.f) v2 = 0.f;
                    S[rr][cc] = f2bf(v2);
                }
    }
    __syncthreads();

    const int r = t >> 1, half = t & 1, c0 = half * 64;
    const long long gr = row0 + r;
    if (mode == 1) {
        if (gr < N) {
            unsigned short* po = outb + gr * DIM + c0;
#pragma unroll
            for (int v = 0; v < 8; ++v)
                *(uint4*)(po + v * 8) = *(const uint4*)&S[r][c0 + v * 8];
        }
    } else {
        // fused concat-readout: s = h0.Wm[0:128] + h1.Wm[128:256] + C.Wm[256:384]
        float s = 0.f;
        if (gr < N) {
            const unsigned short* p0 = hb0 + gr * DIM + c0;
            const unsigned short* p1 = hb1 + gr * DIM + c0;
#pragma unroll
            for (int v = 0; v < 8; ++v) {
                uint4 u0 = *(const uint4*)(p0 + v * 8);
                uint4 u1 = *(const uint4*)(p1 + v * 8);
                const float* wm0 = Wm + c0 + v * 8;
                const float* wm1 = Wm + 128 + c0 + v * 8;
                s += bl(u0.x) * wm0[0] + bh(u0.x) * wm0[1]
                   + bl(u0.y) * wm0[2] + bh(u0.y) * wm0[3]
                   + bl(u0.z) * wm0[4] + bh(u0.z) * wm0[5]
                   + bl(u0.w) * wm0[6] + bh(u0.w) * wm0[7];
                s += bl(u1.x) * wm1[0] + bh(u1.x) * wm1[1]
                   + bl(u1.y) * wm1[2] + bh(u1.y) * wm1[3]
                   + bl(u1.z) * wm1[4] + bh(u1.z) * wm1[5]
                   + bl(u1.w) * wm1[6] + bh(u1.w) * wm1[7];
            }
            const float* wm2 = Wm + 256 + c0;
#pragma unroll
            for (int c = 0; c < 64; ++c)
                s += bfs(S[r][c0 + c]) * wm2[c];
        }
        s += __shfl_xor(s, 1);
        if (half == 0 && gr < N)
            out[gr] = 1.f / (1.f + __expf(-(s + bm[0])));
    }
}

// ---------------------------------------------------------------------------
extern "C" void kernel_launch(void* const* d_in, const int* in_sizes, int n_in,
                              void* d_out, int out_size, void* d_ws, size_t ws_size,
                              hipStream_t stream)
{
    const float* x  = (const float*)d_in[0];
    const int*   ei = (const int*)d_in[1];
    const int*   src = ei;
    const int*   dst = ei + N_EDGES;
    const float* W1[3] = { (const float*)d_in[3], (const float*)d_in[7],  (const float*)d_in[11] };
    const float* b1[3] = { (const float*)d_in[4], (const float*)d_in[8],  (const float*)d_in[12] };
    const float* W2[3] = { (const float*)d_in[5], (const float*)d_in[9],  (const float*)d_in[13] };
    const float* b2[3] = { (const float*)d_in[6], (const float*)d_in[10], (const float*)d_in[14] };
    const float* Wm = (const float*)d_in[15];
    const float* bm = (const float*)d_in[16];
    float* out = (float*)d_out;

    char* p = (char*)d_ws;
    unsigned short* xb = (unsigned short*)p; p += (size_t)N_NODES * DIM * 2;      // 25.6 MB
    unsigned short* hb = (unsigned short*)p; p += (size_t)2 * N_NODES * DIM * 2;  // 51.2 MB
    unsigned short* Wt = (unsigned short*)p; p += (size_t)6 * DIM * DIM * 2;
    int* off  = (int*)p;     p += (size_t)(N_NODES + 1) * sizeof(int);
    int* csr  = (int*)p;     p += (size_t)N_EDGES * sizeof(int);
    int* gcur = (int*)p;     p += (size_t)NB * sizeof(int);
    int* cbase = (int*)p;    p += (size_t)(NB + 1) * sizeof(int);
    unsigned* barr = (unsigned*)p; p += (size_t)NB * BSTR * sizeof(unsigned);

    const int mlp_blocks  = (N_NODES + 127) / 128;         // 782
    const int pa_blocks   = (N_EDGES + CHUNK - 1) / CHUNK; // 391

    // ---- CSR build (bucketed two-pass) ----
    hipMemsetAsync(gcur, 0, (size_t)NB * sizeof(int), stream);
    bucketA_kernel<<<pa_blocks, 256, 0, stream>>>(src, dst, gcur, barr);
    scanb_kernel<<<1, 64, 0, stream>>>(gcur, cbase);
    bucketB_kernel<<<NB, 256, 0, stream>>>(barr, gcur, cbase, off, csr);

    // ---- prep ----
    prep_kernel<<<6250 + 384, 256, 0, stream>>>(
        x, xb, W1[0], W2[0], W1[1], W2[1], W1[2], W2[2], Wt);

    unsigned short* hbuf[2] = { hb, hb + (size_t)N_NODES * DIM };
    const unsigned short* xin_b = xb;
    for (int layer = 0; layer < 3; ++layer) {
        int mode = (layer != 2) ? 1 : 2;
        gin_fused_kernel<<<mlp_blocks, 256, 0, stream>>>(
            xin_b, off, csr,
            Wt + (size_t)(2 * layer) * DIM * DIM, b1[layer],
            Wt + (size_t)(2 * layer + 1) * DIM * DIM, b2[layer],
            (mode == 1) ? hbuf[layer] : (unsigned short*)nullptr,
            hbuf[0], hbuf[1], Wm, bm, out, mode, N_NODES);
        if (mode == 1) xin_b = hbuf[layer];
    }
}

// Round 8
// 468.342 us; speedup vs baseline: 1.6893x; 1.6893x over previous
//
#include <hip/hip_runtime.h>
#include <hip/hip_bf16.h>

#define N_NODES 100000
#define N_EDGES 1600000
#define DIM 128

#define NB    782      // buckets = ceil(100000/128)
#define NPB   128      // nodes per bucket
#define BSTR  2944     // bucket/csr stride (mean 2048, +20 sigma)
#define CHUNK 4096     // edges per bucketA block
#define PA_BLOCKS 391  // ceil(N_EDGES/CHUNK)

typedef __attribute__((ext_vector_type(8))) short bf16x8;
typedef __attribute__((ext_vector_type(4))) float f32x4;

__device__ __forceinline__ short f2bf(float f) {
    union { float f; unsigned u; } v; v.f = f;
    unsigned r = (v.u + 0x7fff + ((v.u >> 16) & 1)) >> 16;
    return (short)r;
}
__device__ __forceinline__ unsigned pk(float lo, float hi) {
    return (unsigned)(unsigned short)f2bf(lo) | ((unsigned)(unsigned short)f2bf(hi) << 16);
}
__device__ __forceinline__ float bl(unsigned p) {
    union { unsigned u; float f; } v; v.u = p << 16; return v.f;
}
__device__ __forceinline__ float bh(unsigned p) {
    union { unsigned u; float f; } v; v.u = p & 0xffff0000u; return v.f;
}
__device__ __forceinline__ float bfs(short s) {
    union { unsigned u; float f; } v; v.u = ((unsigned)(unsigned short)s) << 16; return v.f;
}

// ---------------------------------------------------------------------------
// Fused: bucketA (blocks 0..390) + x f32->bf16 (391..6640) + W transpose
// (6641..7024). bucketA scatters packed recs (src | dlocal<<20) into
// per-bucket arrays at fixed stride BSTR.
// ---------------------------------------------------------------------------
__global__ __launch_bounds__(256) void prepA_kernel(
    const int* __restrict__ src, const int* __restrict__ dst,
    int* __restrict__ gcur, unsigned* __restrict__ barr,
    const float* __restrict__ x, unsigned short* __restrict__ xb,
    const float* __restrict__ W0, const float* __restrict__ W1,
    const float* __restrict__ W2, const float* __restrict__ W3,
    const float* __restrict__ W4, const float* __restrict__ W5,
    unsigned short* __restrict__ T)
{
    __shared__ int cnt[NB];
    __shared__ int base[NB];
    const int b = blockIdx.x, t = threadIdx.x;

    if (b < PA_BLOCKS) {
        const long long e0 = (long long)b * CHUNK;
        const int ecnt = (int)((e0 + CHUNK <= N_EDGES) ? CHUNK : (N_EDGES - e0));
        for (int i = t; i < NB; i += 256) cnt[i] = 0;
        __syncthreads();
        for (int i = t; i < ecnt; i += 256)
            atomicAdd(&cnt[dst[e0 + i] >> 7], 1);
        __syncthreads();
        for (int i = t; i < NB; i += 256) {
            int c = cnt[i];
            base[i] = c ? atomicAdd(&gcur[i], c) : 0;
            cnt[i] = 0;
        }
        __syncthreads();
        for (int i = t; i < ecnt; i += 256) {
            int d = dst[e0 + i], s = src[e0 + i];
            int bk = d >> 7;
            int r = atomicAdd(&cnt[bk], 1);
            barr[(long long)bk * BSTR + base[bk] + r] =
                (unsigned)s | ((unsigned)(d & 127) << 20);
        }
    } else if (b < PA_BLOCKS + 6250) {
        long long i = (long long)(b - PA_BLOCKS) * 256 + t;   // < 1,600,000
        const float4* p = (const float4*)(x + i * 8);
        float4 a = p[0], c = p[1];
        uint4 o;
        o.x = pk(a.x, a.y); o.y = pk(a.z, a.w);
        o.z = pk(c.x, c.y); o.w = pk(c.z, c.w);
        *(uint4*)(xb + i * 8) = o;
    } else {
        int idx = (b - PA_BLOCKS - 6250) * 256 + t;           // 0..98303
        int m = idx >> 14, rem = idx & 16383;
        int n = rem >> 7, k = rem & 127;
        const float* W = (m == 0) ? W0 : (m == 1) ? W1 : (m == 2) ? W2
                       : (m == 3) ? W3 : (m == 4) ? W4 : W5;
        T[(size_t)m * DIM * DIM + n * DIM + k] = (unsigned short)f2bf(W[k * DIM + n]);
    }
}

// ---------------------------------------------------------------------------
// bucketB: per-bucket counting sort -> rng[node]={beg,end}, csr (strided)
// ---------------------------------------------------------------------------
__global__ __launch_bounds__(256) void bucketB_kernel(
    const unsigned* __restrict__ barr, const int* __restrict__ gcur,
    int2* __restrict__ rng, int* __restrict__ csr)
{
    __shared__ int cnt[NPB];
    __shared__ int cur[NPB];
    __shared__ int sn;
    const int b = blockIdx.x, t = threadIdx.x;
    const int sbase = b * BSTR;
    if (t < NPB) cnt[t] = 0;
    if (t == 0) sn = gcur[b];
    __syncthreads();
    const int n = sn;
    const unsigned* be = barr + (long long)b * BSTR;
    for (int i = t; i < n; i += 256)
        atomicAdd(&cnt[(be[i] >> 20) & 127], 1);
    __syncthreads();
    if (t < 64) {
        int carry = 0;
#pragma unroll
        for (int k = 0; k < 2; ++k) {
            int idx = k * 64 + t;
            int v = cnt[idx], s = v;
#pragma unroll
            for (int ofs = 1; ofs < 64; ofs <<= 1) {
                int u = __shfl_up(s, ofs);
                if (t >= ofs) s += u;
            }
            cur[idx] = carry + s - v;
            carry += __shfl(s, 63);
        }
    }
    __syncthreads();
    if (t < NPB) {
        int node = b * NPB + t;
        if (node < N_NODES) {
            int beg = sbase + cur[t];
            rng[node] = make_int2(beg, beg + cnt[t]);
        }
    }
    __syncthreads();
    for (int i = t; i < n; i += 256) {
        unsigned r = be[i];
        int j = (r >> 20) & 127;
        int p = atomicAdd(&cur[j], 1);
        csr[sbase + p] = (int)(r & 0xFFFFF);
    }
}

// ---------------------------------------------------------------------------
// Pull aggregation (bf16): ab[n] = bf16( xin[n] + sum_{j in adj} xin[j] )
// One wave per node; 4 edge-groups x 16 lanes x 16B; 4-deep unroll.
// ---------------------------------------------------------------------------
__global__ __launch_bounds__(256) void gather_kernel(
    const unsigned short* __restrict__ xb,
    const int2* __restrict__ rng, const int* __restrict__ csr,
    unsigned short* __restrict__ ab)
{
    long long gt = (long long)blockIdx.x * 256 + threadIdx.x;
    int node = (int)(gt >> 6);
    int lane = (int)(gt & 63);
    if (node >= N_NODES) return;
    const int g = lane >> 4, l4 = lane & 15;
    const int2 be = rng[node];
    const int beg = be.x, end = be.y;
    float acc[8] = {0.f, 0.f, 0.f, 0.f, 0.f, 0.f, 0.f, 0.f};
    int j = beg + g;
    for (; j + 12 < end; j += 16) {
        int s0 = csr[j], s1 = csr[j + 4], s2 = csr[j + 8], s3 = csr[j + 12];
        uint4 v0 = *(const uint4*)(xb + (long long)s0 * DIM + l4 * 8);
        uint4 v1 = *(const uint4*)(xb + (long long)s1 * DIM + l4 * 8);
        uint4 v2 = *(const uint4*)(xb + (long long)s2 * DIM + l4 * 8);
        uint4 v3 = *(const uint4*)(xb + (long long)s3 * DIM + l4 * 8);
        acc[0] += (bl(v0.x) + bl(v1.x)) + (bl(v2.x) + bl(v3.x));
        acc[1] += (bh(v0.x) + bh(v1.x)) + (bh(v2.x) + bh(v3.x));
        acc[2] += (bl(v0.y) + bl(v1.y)) + (bl(v2.y) + bl(v3.y));
        acc[3] += (bh(v0.y) + bh(v1.y)) + (bh(v2.y) + bh(v3.y));
        acc[4] += (bl(v0.z) + bl(v1.z)) + (bl(v2.z) + bl(v3.z));
        acc[5] += (bh(v0.z) + bh(v1.z)) + (bh(v2.z) + bh(v3.z));
        acc[6] += (bl(v0.w) + bl(v1.w)) + (bl(v2.w) + bl(v3.w));
        acc[7] += (bh(v0.w) + bh(v1.w)) + (bh(v2.w) + bh(v3.w));
    }
    for (; j < end; j += 4) {
        int s = csr[j];
        uint4 v = *(const uint4*)(xb + (long long)s * DIM + l4 * 8);
        acc[0] += bl(v.x); acc[1] += bh(v.x);
        acc[2] += bl(v.y); acc[3] += bh(v.y);
        acc[4] += bl(v.z); acc[5] += bh(v.z);
        acc[6] += bl(v.w); acc[7] += bh(v.w);
    }
#pragma unroll
    for (int k = 0; k < 8; ++k) {
        acc[k] += __shfl_xor(acc[k], 16);
        acc[k] += __shfl_xor(acc[k], 32);
    }
    if (g == 0) {
        uint4 sv = *(const uint4*)(xb + (long long)node * DIM + l4 * 8);
        acc[0] += bl(sv.x); acc[1] += bh(sv.x);
        acc[2] += bl(sv.y); acc[3] += bh(sv.y);
        acc[4] += bl(sv.z); acc[5] += bh(sv.z);
        acc[6] += bl(sv.w); acc[7] += bh(sv.w);
        uint4 o;
        o.x = pk(acc[0], acc[1]); o.y = pk(acc[2], acc[3]);
        o.z = pk(acc[4], acc[5]); o.w = pk(acc[6], acc[7]);
        *(uint4*)(ab + (long long)node * DIM + l4 * 8) = o;
    }
}

// ---------------------------------------------------------------------------
// Fused GIN MLP, single 35KB LDS buffer (4 blocks/CU).
// mode 1: store bf16 relu(out) to outb  (layers 0,1)
// mode 2: final layer -> fused concat-readout: out[n]=sigmoid(cat.Wm+bm)
// ---------------------------------------------------------------------------
__global__ __launch_bounds__(256) void gin_mlp_kernel(
    const unsigned short* __restrict__ ab,
    const unsigned short* __restrict__ Wt1, const float* __restrict__ b1,
    const unsigned short* __restrict__ Wt2, const float* __restrict__ b2,
    unsigned short* __restrict__ outb,
    const unsigned short* __restrict__ hb0, const unsigned short* __restrict__ hb1,
    const float* __restrict__ Wm, const float* __restrict__ bm,
    float* __restrict__ out, int mode, int N)
{
    __shared__ short S[128][136];   // A -> H -> C in turn

    const int t = threadIdx.x;
    const long long row0 = (long long)blockIdx.x * 128;
    const int r = t >> 1, half = t & 1, c0 = half * 64;
    const long long gr = row0 + r;

    // ---- stage A ----
    if (gr < N) {
        const unsigned short* pa = ab + gr * DIM + c0;
#pragma unroll
        for (int v = 0; v < 8; ++v)
            *(uint4*)&S[r][c0 + v * 8] = *(const uint4*)(pa + v * 8);
    } else {
#pragma unroll
        for (int v = 0; v < 8; ++v)
            *(uint4*)&S[r][c0 + v * 8] = make_uint4(0, 0, 0, 0);
    }
    __syncthreads();

    const int w = t >> 6, lane = t & 63;
    const int wr = (w >> 1) * 64, wc = (w & 1) * 64;
    const int fr = lane & 15, kg = lane >> 4;

    // ---- GEMM1: H = relu(A @ W1 + b1) ----
    f32x4 acc[4][4] = {};
#pragma unroll
    for (int k0 = 0; k0 < 128; k0 += 32) {
        bf16x8 a[4], b[4];
#pragma unroll
        for (int mi = 0; mi < 4; ++mi)
            a[mi] = *(const bf16x8*)&S[wr + mi * 16 + fr][k0 + kg * 8];
#pragma unroll
        for (int ni = 0; ni < 4; ++ni)
            b[ni] = *(const bf16x8*)(Wt1 + (long long)(wc + ni * 16 + fr) * DIM + k0 + kg * 8);
#pragma unroll
        for (int mi = 0; mi < 4; ++mi)
#pragma unroll
            for (int ni = 0; ni < 4; ++ni)
                acc[mi][ni] = __builtin_amdgcn_mfma_f32_16x16x32_bf16(
                    a[mi], b[ni], acc[mi][ni], 0, 0, 0);
    }
    __syncthreads();

    {
        float bia[4];
#pragma unroll
        for (int ni = 0; ni < 4; ++ni) bia[ni] = b1[wc + ni * 16 + fr];
#pragma unroll
        for (int mi = 0; mi < 4; ++mi)
#pragma unroll
            for (int ni = 0; ni < 4; ++ni)
#pragma unroll
                for (int j = 0; j < 4; ++j) {
                    int rr = wr + mi * 16 + kg * 4 + j;
                    int cc = wc + ni * 16 + fr;
                    float hv = acc[mi][ni][j] + bia[ni];
                    S[rr][cc] = f2bf(hv > 0.f ? hv : 0.f);
                }
    }
    __syncthreads();

    // ---- GEMM2: C = H @ W2 + b2 ----
    f32x4 acc2[4][4] = {};
#pragma unroll
    for (int k0 = 0; k0 < 128; k0 += 32) {
        bf16x8 a[4], b[4];
#pragma unroll
        for (int mi = 0; mi < 4; ++mi)
            a[mi] = *(const bf16x8*)&S[wr + mi * 16 + fr][k0 + kg * 8];
#pragma unroll
        for (int ni = 0; ni < 4; ++ni)
            b[ni] = *(const bf16x8*)(Wt2 + (long long)(wc + ni * 16 + fr) * DIM + k0 + kg * 8);
#pragma unroll
        for (int mi = 0; mi < 4; ++mi)
#pragma unroll
            for (int ni = 0; ni < 4; ++ni)
                acc2[mi][ni] = __builtin_amdgcn_mfma_f32_16x16x32_bf16(
                    a[mi], b[ni], acc2[mi][ni], 0, 0, 0);
    }
    __syncthreads();

    {
        float bia[4];
#pragma unroll
        for (int ni = 0; ni < 4; ++ni) bia[ni] = b2[wc + ni * 16 + fr];
#pragma unroll
        for (int mi = 0; mi < 4; ++mi)
#pragma unroll
            for (int ni = 0; ni < 4; ++ni)
#pragma unroll
                for (int j = 0; j < 4; ++j) {
                    int rr = wr + mi * 16 + kg * 4 + j;
                    int cc = wc + ni * 16 + fr;
                    float v2 = acc2[mi][ni][j] + bia[ni];
                    if (mode == 1 && v2 < 0.f) v2 = 0.f;
                    S[rr][cc] = f2bf(v2);
                }
    }
    __syncthreads();

    if (mode == 1) {
        if (gr < N) {
            unsigned short* po = outb + gr * DIM + c0;
#pragma unroll
            for (int v = 0; v < 8; ++v)
                *(uint4*)(po + v * 8) = *(const uint4*)&S[r][c0 + v * 8];
        }
    } else {
        // fused concat-readout: s = h0.Wm[0:128] + h1.Wm[128:256] + C.Wm[256:384]
        float s = 0.f;
        if (gr < N) {
            const unsigned short* p0 = hb0 + gr * DIM + c0;
            const unsigned short* p1 = hb1 + gr * DIM + c0;
#pragma unroll
            for (int v = 0; v < 8; ++v) {
                uint4 u0 = *(const uint4*)(p0 + v * 8);
                uint4 u1 = *(const uint4*)(p1 + v * 8);
                const float* wm0 = Wm + c0 + v * 8;
                const float* wm1 = Wm + 128 + c0 + v * 8;
                s += bl(u0.x) * wm0[0] + bh(u0.x) * wm0[1]
                   + bl(u0.y) * wm0[2] + bh(u0.y) * wm0[3]
                   + bl(u0.z) * wm0[4] + bh(u0.z) * wm0[5]
                   + bl(u0.w) * wm0[6] + bh(u0.w) * wm0[7];
                s += bl(u1.x) * wm1[0] + bh(u1.x) * wm1[1]
                   + bl(u1.y) * wm1[2] + bh(u1.y) * wm1[3]
                   + bl(u1.z) * wm1[4] + bh(u1.z) * wm1[5]
                   + bl(u1.w) * wm1[6] + bh(u1.w) * wm1[7];
            }
            const float* wm2 = Wm + 256 + c0;
#pragma unroll
            for (int c = 0; c < 64; ++c)
                s += bfs(S[r][c0 + c]) * wm2[c];
        }
        s += __shfl_xor(s, 1);
        if (half == 0 && gr < N)
            out[gr] = 1.f / (1.f + __expf(-(s + bm[0])));
    }
}

// ---------------------------------------------------------------------------
extern "C" void kernel_launch(void* const* d_in, const int* in_sizes, int n_in,
                              void* d_out, int out_size, void* d_ws, size_t ws_size,
                              hipStream_t stream)
{
    const float* x  = (const float*)d_in[0];
    const int*   ei = (const int*)d_in[1];
    const int*   src = ei;
    const int*   dst = ei + N_EDGES;
    const float* W1[3] = { (const float*)d_in[3], (const float*)d_in[7],  (const float*)d_in[11] };
    const float* b1[3] = { (const float*)d_in[4], (const float*)d_in[8],  (const float*)d_in[12] };
    const float* W2[3] = { (const float*)d_in[5], (const float*)d_in[9],  (const float*)d_in[13] };
    const float* b2[3] = { (const float*)d_in[6], (const float*)d_in[10], (const float*)d_in[14] };
    const float* Wm = (const float*)d_in[15];
    const float* bm = (const float*)d_in[16];
    float* out = (float*)d_out;

    char* p = (char*)d_ws;
    unsigned short* xb = (unsigned short*)p; p += (size_t)N_NODES * DIM * 2;      // 25.6 MB
    unsigned short* ab = (unsigned short*)p; p += (size_t)N_NODES * DIM * 2;      // 25.6 MB
    unsigned short* hb = (unsigned short*)p; p += (size_t)2 * N_NODES * DIM * 2;  // 51.2 MB
    unsigned short* Wt = (unsigned short*)p; p += (size_t)6 * DIM * DIM * 2;
    int2* rng = (int2*)p;    p += (size_t)N_NODES * sizeof(int2);
    int* csr  = (int*)p;     p += (size_t)NB * BSTR * sizeof(int);                // 9.2 MB strided
    int* gcur = (int*)p;     p += (size_t)NB * sizeof(int);
    unsigned* barr = (unsigned*)p; p += (size_t)NB * BSTR * sizeof(unsigned);     // 9.2 MB

    const int mlp_blocks  = (N_NODES + 127) / 128;         // 782
    const int wave_blocks = (N_NODES * 64 + 255) / 256;    // 25000
    const int prepA_blocks = PA_BLOCKS + 6250 + 384;       // 7025

    // ---- CSR build + prep (fused) ----
    hipMemsetAsync(gcur, 0, (size_t)NB * sizeof(int), stream);
    prepA_kernel<<<prepA_blocks, 256, 0, stream>>>(
        src, dst, gcur, barr, x, xb,
        W1[0], W2[0], W1[1], W2[1], W1[2], W2[2], Wt);
    bucketB_kernel<<<NB, 256, 0, stream>>>(barr, gcur, rng, csr);

    unsigned short* hbuf[2] = { hb, hb + (size_t)N_NODES * DIM };
    const unsigned short* xin_b = xb;
    for (int layer = 0; layer < 3; ++layer) {
        gather_kernel<<<wave_blocks, 256, 0, stream>>>(xin_b, rng, csr, ab);
        int mode = (layer != 2) ? 1 : 2;
        gin_mlp_kernel<<<mlp_blocks, 256, 0, stream>>>(
            ab, Wt + (size_t)(2 * layer) * DIM * DIM, b1[layer],
            Wt + (size_t)(2 * layer + 1) * DIM * DIM, b2[layer],
            (mode == 1) ? hbuf[layer] : (unsigned short*)nullptr,
            hbuf[0], hbuf[1], Wm, bm, out, mode, N_NODES);
        if (mode == 1) xin_b = hbuf[layer];
    }
}